// Round 16
// baseline (3522.466 us; speedup 1.0000x reference)
//
#include <hip/hip_runtime.h>

#define DEVI __device__ __forceinline__

typedef __attribute__((ext_vector_type(8))) __bf16 bf16x8;
typedef __attribute__((ext_vector_type(4))) float f32x4;

// ---------- scalar helpers ----------
DEVI unsigned short f2b(float f) {           // f32 -> bf16 (RNE)
  unsigned u = __float_as_uint(f);
  u = u + 0x7fffu + ((u >> 16) & 1u);
  return (unsigned short)(u >> 16);
}
DEVI float lo16(unsigned u) { return __uint_as_float(u << 16); }
DEVI float hi16(unsigned u) { return __uint_as_float(u & 0xffff0000u); }
#if __has_builtin(__builtin_amdgcn_rcpf)
DEVI float rcpf(float x) { return __builtin_amdgcn_rcpf(x); }
#else
DEVI float rcpf(float x) { return 1.f / x; }
#endif
DEVI float sigm(float x) { return rcpf(1.f + __expf(-x)); }
DEVI float tanh_f(float x) { return fmaf(2.f, rcpf(1.f + __expf(-2.f * x)), -1.f); }

// ---------- fp8 e4m3fn encode ----------
#if __has_builtin(__builtin_amdgcn_cvt_pk_fp8_f32)
DEVI unsigned char f2e4m3(float f) {
  return (unsigned char)(__builtin_amdgcn_cvt_pk_fp8_f32(f, f, 0, false) & 0xff);
}
#else
DEVI unsigned char f2e4m3(float f) {   // software RNE e4m3fn
  unsigned u = __float_as_uint(f);
  unsigned s = (u >> 31) << 7;
  float a = fabsf(f);
  if (a >= 448.f) return (unsigned char)(s | 0x7e);
  if (a < 0.015625f) {                 // denorm, unit 2^-9
    int m = (int)rintf(a * 512.f);
    if (m >= 8) return (unsigned char)(s | 0x08);
    return (unsigned char)(s | m);
  }
  unsigned ur = u + 0x7FFFF + ((u >> 20) & 1);   // RNE at mantissa bit 20
  int e8 = (int)((ur >> 23) & 255) - 127 + 7;
  unsigned m3 = (ur >> 20) & 7;
  if (e8 > 15 || (e8 == 15 && m3 > 6)) return (unsigned char)(s | 0x7e);
  if (e8 <= 0) return (unsigned char)s;
  return (unsigned char)(s | (e8 << 3) | m3);
}
#endif

// ---------- prep kernels ----------
__global__ void cvt_bf16(const float* __restrict__ in, unsigned short* __restrict__ out, int n) {
  for (int i = blockIdx.x * blockDim.x + threadIdx.x; i < n; i += gridDim.x * blockDim.x)
    out[i] = f2b(in[i]);
}

// Whh (2,1024,256) f32 -> fp8 MFMA-A-fragment order:
// uint2 index = ((d*64 + mt)*8 + kf)*64 + lane; bytes j=0..7:
//   row = mt*16 + (lane&15); unit = row>>2; gate = row&3;
//   k = kf*32 + (lane>>4)*8 + j;  src = W[d][gate*256 + unit][k]
__global__ void whh_pack(const float* __restrict__ W, uint2* __restrict__ out) {
  int idx = blockIdx.x * blockDim.x + threadIdx.x;   // 65536 total
  if (idx >= 65536) return;
  int d = idx >> 15, rem = idx & 32767;
  int mt = rem >> 9, kf = (rem >> 6) & 7, lane = rem & 63;
  int row = mt * 16 + (lane & 15);
  int unit = row >> 2, gate = row & 3;
  int kb = kf * 32 + (lane >> 4) * 8;
  const float* w = W + (((size_t)d * 1024 + gate * 256 + unit) * 256 + kb);
  unsigned lo = 0, hi = 0;
  #pragma unroll
  for (int j = 0; j < 4; ++j) lo |= (unsigned)f2e4m3(w[j]) << (8 * j);
  #pragma unroll
  for (int j = 0; j < 4; ++j) hi |= (unsigned)f2e4m3(w[4 + j]) << (8 * j);
  out[idx] = make_uint2(lo, hi);
}

__global__ void bias_sum(const float* __restrict__ a, const float* __restrict__ b,
                         float* __restrict__ o, int n) {
  int i = blockIdx.x * blockDim.x + threadIdx.x;
  if (i < n) o[i] = a[i] + b[i];
}

__global__ void embed_gather(const int* __restrict__ ids, const float* __restrict__ tab,
                             unsigned short* __restrict__ out, int total) {
  for (int i = blockIdx.x * blockDim.x + threadIdx.x; i < total; i += gridDim.x * blockDim.x) {
    int bt = i >> 7, c = i & 127;
    out[i] = f2b(tab[(size_t)ids[bt] * 128 + c]);
  }
}

// ---------- GEMM (LDS-staged): C[M,N] = act(A[M,K](lda,bf16) @ W[N,K]^T + bias) -> bf16
// 128x128 tile, 256 thr (4 waves), K-step 32. (R11, measured good.)
template <int ACT, int PERM>
__global__ __launch_bounds__(256) void gemm_lds(const unsigned short* __restrict__ A, int lda,
                                                const unsigned short* __restrict__ W,
                                                const float* __restrict__ bias,
                                                unsigned short* __restrict__ C,
                                                int M, int N, int K) {
  const int ntiles = N >> 7;
  const int mt = blockIdx.x / ntiles;
  const int nt = blockIdx.x - mt * ntiles;
  const int m0 = mt << 7, n0 = nt << 7;
  const int tid = threadIdx.x;
  const int w = tid >> 6, lane = tid & 63, r = lane & 15, q = lane >> 4;
  __shared__ unsigned short lsA[4096], lsB[4096];
  f32x4 acc[16];
  #pragma unroll
  for (int i = 0; i < 16; ++i) acc[i] = f32x4{0.f, 0.f, 0.f, 0.f};

  const int srow = tid >> 2, sq = tid & 3;
  const int s0 = (srow << 2) | (sq ^ (srow & 3) ^ ((srow >> 2) & 3));
  const unsigned short* gA = A + (size_t)(m0 + srow) * lda + sq * 8;
  const unsigned short* gB = W + (size_t)(n0 + srow) * K + sq * 8;
  const size_t gAs = (size_t)64 * lda, gBs = (size_t)64 * K;
  const int sw = q ^ (r & 3) ^ ((r >> 2) & 3);

  for (int k0 = 0; k0 < K; k0 += 32) {
    uint4 va0 = *(const uint4*)(gA + k0);
    uint4 va1 = *(const uint4*)(gA + gAs + k0);
    uint4 vb0 = *(const uint4*)(gB + k0);
    uint4 vb1 = *(const uint4*)(gB + gBs + k0);
    *(uint4*)(lsA + s0 * 8) = va0;
    *(uint4*)(lsA + s0 * 8 + 2048) = va1;
    *(uint4*)(lsB + s0 * 8) = vb0;
    *(uint4*)(lsB + s0 * 8 + 2048) = vb1;
    __syncthreads();
    const bf16x8 a0 = *(const bf16x8*)(const void*)(lsA + ((w * 32 + r) * 4 + sw) * 8);
    const bf16x8 a1 = *(const bf16x8*)(const void*)(lsA + ((w * 32 + 16 + r) * 4 + sw) * 8);
    #pragma unroll
    for (int nf = 0; nf < 8; ++nf) {
      const bf16x8 b = *(const bf16x8*)(const void*)(lsB + ((nf * 16 + r) * 4 + sw) * 8);
      acc[nf]     = __builtin_amdgcn_mfma_f32_16x16x32_bf16(a0, b, acc[nf], 0, 0, 0);
      acc[8 + nf] = __builtin_amdgcn_mfma_f32_16x16x32_bf16(a1, b, acc[8 + nf], 0, 0, 0);
    }
    __syncthreads();
  }
  #pragma unroll
  for (int mf = 0; mf < 2; ++mf) {
    const int rbase = m0 + w * 32 + mf * 16 + q * 4;
    #pragma unroll
    for (int nf = 0; nf < 8; ++nf) {
      const f32x4 a = acc[mf * 8 + nf];
      const int col = n0 + nf * 16 + r;
      const float bv = bias[col];
      int oc = col;
      if constexpr (PERM) oc = (col & 1024) | ((col & 255) << 2) | ((col >> 8) & 3);
      #pragma unroll
      for (int i = 0; i < 4; ++i) {
        float v = a[i] + bv;
        if constexpr (ACT) v = fmaxf(v, 0.f);
        C[(size_t)(rbase + i) * N + oc] = f2b(v);
      }
    }
  }
}

// ---------- LSTM recurrence via MFMA fp8, 16 samples per block ----------
// R15 form + ONE change: in-loop barrier is lgkmcnt-only (LDS visibility) so output
// stores and weight/xg loads stay in flight across the barrier (no vmcnt(0) drain).
// wreg[32] preload: remat'd by the compiler into one early per-iteration load batch
// (max bytes in flight) -- measured 1213-1215us vs 1487 for in-loop indexed loads.
__global__ __launch_bounds__(1024, 4) void lstm_mfma(
    const uint2* __restrict__ W0, const unsigned short* __restrict__ x0,
    unsigned short* __restrict__ o0, int oo0,
    const uint2* __restrict__ W1, const unsigned short* __restrict__ x1,
    unsigned short* __restrict__ o1, int oo1, int T) {
  const int bid = blockIdx.x;
  const int sg = bid & 3, dir = (bid >> 2) & 1, grp = bid >> 3;
  const uint2* __restrict__ Wp = (grp ? W1 : W0) + (size_t)dir * 32768;
  const unsigned short* __restrict__ xg = grp ? x1 : x0;
  unsigned short* __restrict__ out = grp ? o1 : o0;
  const int outOff = grp ? oo1 : oo0;

  const int tid = threadIdx.x;
  const int w = tid >> 6, lane = tid & 63, q = lane >> 4, n = lane & 15;
  const int b = sg * 16 + n;

  __shared__ long hb[2][512];                 // fp8 h B-fragments (MFMA input)
  __shared__ unsigned short hout[2][16][264]; // bf16 h rows, padded (store staging)
  hb[0][tid & 511] = 0;
  hb[1][tid & 511] = 0;

  // ---- preload this wave's Whh slice (scheduling effect; do not remove) ----
  long wreg[32];
  {
    const uint2* ap = Wp + (size_t)(w * 32) * 64 + lane;
    #pragma unroll
    for (int i = 0; i < 32; ++i)
      wreg[i] = __builtin_bit_cast(long, ap[(size_t)i * 64]);
  }

  float c[4] = {0.f, 0.f, 0.f, 0.f};
  const unsigned short* xb = xg + ((size_t)b * T) * 2048 + dir * 1024 + (w * 16 + q) * 4;
  // wave w cooperatively stores sample (sg*16+w)'s output row
  unsigned short* orow = out + ((size_t)(sg * 16 + w) * T) * 1024 + outOff + dir * 256 + lane * 4;

  const int tstep = dir ? -1 : 1;
  int t = dir ? T - 1 : 0;
  // prefetch first step's xg
  uint2 xv[4];
  #pragma unroll
  for (int j = 0; j < 4; ++j)
    xv[j] = *(const uint2*)(xb + (size_t)t * 2048 + j * 16);
  __syncthreads();

  int cur = 0;
  for (int ti = 0; ti < T; ++ti) {
    // coalesced store of previous step's h (written into hout[cur] last iter)
    if (ti) {
      const uint2 hv = *(const uint2*)&hout[cur][w][lane * 4];
      *(uint2*)(orow + (size_t)(t - tstep) * 1024) = hv;
    }
    // prefetch next step's xg (consumed after next barrier)
    uint2 xn[4];
    if (ti + 1 < T) {
      #pragma unroll
      for (int j = 0; j < 4; ++j)
        xn[j] = *(const uint2*)(xb + (size_t)(t + tstep) * 2048 + j * 16);
    }
    // MFMA: acc[j] = Whh-tile(w*4+j) x h
    f32x4 acc[4];
    #pragma unroll
    for (int j = 0; j < 4; ++j) acc[j] = f32x4{0.f, 0.f, 0.f, 0.f};
    #pragma unroll
    for (int kf = 0; kf < 8; ++kf) {
      const long bf = hb[cur][kf * 64 + q * 16 + n];
      #pragma unroll
      for (int j = 0; j < 4; ++j)
        acc[j] = __builtin_amdgcn_mfma_f32_16x16x32_fp8_fp8(wreg[j * 8 + kf], bf, acc[j], 0, 0, 0);
    }
    // cell update: lane owns (unit u, sample n) fully
    unsigned char* hw = (unsigned char*)&hb[cur ^ 1][0];
    #pragma unroll
    for (int j = 0; j < 4; ++j) {
      const int u = w * 16 + j * 4 + q;
      const float gi = acc[j][0] + lo16(xv[j].x);
      const float gf = acc[j][1] + hi16(xv[j].x);
      const float gg = acc[j][2] + lo16(xv[j].y);
      const float go = acc[j][3] + hi16(xv[j].y);
      c[j] = sigm(gf) * c[j] + sigm(gi) * tanh_f(gg);
      const float h = sigm(go) * tanh_f(c[j]);
      hw[(u >> 3) * 128 + n * 8 + (u & 7)] = f2e4m3(h);
      hout[cur ^ 1][n][u] = f2b(h);
    }
    // lgkmcnt-only barrier: LDS writes visible; global stores/loads NOT drained
    asm volatile("s_waitcnt lgkmcnt(0)\n\ts_barrier" ::: "memory");
    #pragma unroll
    for (int j = 0; j < 4; ++j) xv[j] = xn[j];
    t += tstep;
    cur ^= 1;
  }
  // epilogue: store last step's h
  const uint2 hv = *(const uint2*)&hout[cur][w][lane * 4];
  *(uint2*)(orow + (size_t)(t - tstep) * 1024) = hv;
}

// ---------- classifier layer 2 ----------
__global__ __launch_bounds__(256) void cls2_kernel(const unsigned short* __restrict__ h1,
                                                   const unsigned short* __restrict__ w2,
                                                   const float* __restrict__ b2,
                                                   float* __restrict__ logits, int M) {
  int idx = blockIdx.x * 256 + threadIdx.x;
  int row = idx >> 4, n = idx & 15;
  if (row >= M || n >= 15) return;
  const unsigned* hp = (const unsigned*)(h1 + (size_t)row * 512);
  const unsigned* wp = (const unsigned*)(w2 + (size_t)n * 512);
  float acc = 0.f;
  #pragma unroll 8
  for (int k = 0; k < 256; ++k) {
    unsigned uh = hp[k], uw = wp[k];
    acc = fmaf(lo16(uh), lo16(uw), acc);
    acc = fmaf(hi16(uh), hi16(uw), acc);
  }
  logits[(size_t)row * 16 + n] = acc + b2[n];
}

// ---------- CRF ----------
__global__ __launch_bounds__(256) void crf_num(const float* __restrict__ logits,
                                               const int* __restrict__ tags,
                                               const float* __restrict__ start,
                                               const float* __restrict__ end,
                                               const float* __restrict__ trans,
                                               float* __restrict__ numout, int T) {
  int b = blockIdx.x, tid = threadIdx.x;
  const int* tg = tags + (size_t)b * T;
  float s = 0.f;
  for (int t = tid; t < T; t += 256) {
    int cur = tg[t];
    s += logits[((size_t)b * T + t) * 16 + cur];
    if (t > 0) s += trans[tg[t - 1] * 15 + cur];
  }
  #pragma unroll
  for (int off = 32; off > 0; off >>= 1) s += __shfl_down(s, off, 64);
  __shared__ float red[4];
  if ((tid & 63) == 0) red[tid >> 6] = s;
  __syncthreads();
  if (tid == 0)
    numout[b] = red[0] + red[1] + red[2] + red[3] + start[tg[0]] + end[tg[T - 1]];
}

__global__ void crf_denom(const float* __restrict__ logits, const float* __restrict__ start,
                          const float* __restrict__ end, const float* __restrict__ trans,
                          float* __restrict__ denout, int T) {
  int b = blockIdx.x;
  int lane = threadIdx.x;
  int kp = lane < 15 ? lane : 0;
  float tcol[15];
  #pragma unroll
  for (int k = 0; k < 15; ++k) tcol[k] = trans[k * 15 + kp];
  float score = start[kp] + logits[((size_t)b * T) * 16 + kp];
  for (int t = 1; t < T; ++t) {
    float e = logits[((size_t)b * T + t) * 16 + kp];
    float s[15], m = -3.4e38f;
    #pragma unroll
    for (int k = 0; k < 15; ++k) {
      s[k] = __shfl(score, k, 64) + tcol[k];
      m = fmaxf(m, s[k]);
    }
    float sum = 0.f;
    #pragma unroll
    for (int k = 0; k < 15; ++k) sum += __expf(s[k] - m);
    score = e + m + __logf(sum);
  }
  float x = score + end[kp];
  float m = -3.4e38f;
  #pragma unroll
  for (int k = 0; k < 15; ++k) m = fmaxf(m, __shfl(x, k, 64));
  float sum = 0.f;
  #pragma unroll
  for (int k = 0; k < 15; ++k) sum += __expf(__shfl(x, k, 64) - m);
  if (lane == 0) denout[b] = m + __logf(sum);
}

__global__ void crf_final(const float* __restrict__ num, const float* __restrict__ den,
                          float* __restrict__ out) {
  int l = threadIdx.x;
  float v = den[l] - num[l];
  #pragma unroll
  for (int off = 32; off > 0; off >>= 1) v += __shfl_xor(v, off, 64);
  if (l == 0) out[0] = v * (1.f / 64.f);
}

// ---------- host ----------
extern "C" void kernel_launch(void* const* d_in, const int* in_sizes, int n_in,
                              void* d_out, int out_size, void* d_ws, size_t ws_size,
                              hipStream_t stream) {
  const int B = 64, T = 512, M = B * T;   // 32768
  const float* we   = (const float*)d_in[1];
  const int*   cid  = (const int*)d_in[0];
  const int*   tags = (const int*)d_in[2];
  const float* etab = (const float*)d_in[3];

  char* ws = (char*)d_ws;
  size_t off = 0;
  auto alloc = [&](size_t bytes) -> char* {
    char* p = ws + off;
    off += (bytes + 255) & ~(size_t)255;
    return p;
  };
  // small, permanent
  unsigned short* wih_c0 = (unsigned short*)alloc((size_t)2048 * 128 * 2);
  unsigned short* wih_c1 = (unsigned short*)alloc((size_t)2048 * 512 * 2);
  unsigned short* wih_w0 = (unsigned short*)alloc((size_t)2048 * 768 * 2);
  unsigned short* wih_w1 = (unsigned short*)alloc((size_t)2048 * 512 * 2);
  unsigned short* cls1b  = (unsigned short*)alloc((size_t)512 * 1024 * 2);
  unsigned short* cls2b  = (unsigned short*)alloc((size_t)15 * 512 * 2);
  uint2* whh_c0 = (uint2*)alloc((size_t)65536 * 8);
  uint2* whh_c1 = (uint2*)alloc((size_t)65536 * 8);
  uint2* whh_w0 = (uint2*)alloc((size_t)65536 * 8);
  uint2* whh_w1 = (uint2*)alloc((size_t)65536 * 8);
  float* bs_c0 = (float*)alloc(2048 * 4);
  float* bs_c1 = (float*)alloc(2048 * 4);
  float* bs_w0 = (float*)alloc(2048 * 4);
  float* bs_w1 = (float*)alloc(2048 * 4);
  float* numb = (float*)alloc(64 * 4);
  float* denb = (float*)alloc(64 * 4);
  // big
  unsigned short* comb = (unsigned short*)alloc((size_t)M * 1024 * 2);   // 64 MB
  unsigned short* xg_c = (unsigned short*)alloc((size_t)M * 2048 * 2);   // 128 MB
  const size_t xgw_bytes = (size_t)M * 2048 * 2;
  const bool fused = (off + xgw_bytes) <= ws_size;
  unsigned short* xg_w;
  unsigned short* ce_b;
  unsigned short* we_b;
  if (fused) {
    xg_w = (unsigned short*)alloc(xgw_bytes);
    ce_b = xg_w;          // consumed by g_c0 before g_w0 overwrites xg_w
    we_b = comb;          // consumed by g_w0 before lstm0 writes comb
  } else {
    xg_w = xg_c;
    ce_b = (unsigned short*)alloc((size_t)M * 128 * 2);
    we_b = (unsigned short*)alloc((size_t)M * 768 * 2);
  }
  unsigned short* h1 = xg_c;                        // free after level-1 lstm
  float* logits = (float*)(xg_c + (size_t)24 * 1024 * 1024);   // +48MB into xg_c

  // ---- prep ----
  cvt_bf16<<<1024, 256, 0, stream>>>((const float*)d_in[4],  wih_c0, 2048 * 128);
  cvt_bf16<<<1024, 256, 0, stream>>>((const float*)d_in[8],  wih_c1, 2048 * 512);
  cvt_bf16<<<1024, 256, 0, stream>>>((const float*)d_in[12], wih_w0, 2048 * 768);
  cvt_bf16<<<1024, 256, 0, stream>>>((const float*)d_in[16], wih_w1, 2048 * 512);
  cvt_bf16<<<1024, 256, 0, stream>>>((const float*)d_in[20], cls1b, 512 * 1024);
  cvt_bf16<<<64, 256, 0, stream>>>((const float*)d_in[22], cls2b, 15 * 512);
  cvt_bf16<<<4096, 256, 0, stream>>>(we, we_b, M * 768);
  whh_pack<<<256, 256, 0, stream>>>((const float*)d_in[5],  whh_c0);
  whh_pack<<<256, 256, 0, stream>>>((const float*)d_in[9],  whh_c1);
  whh_pack<<<256, 256, 0, stream>>>((const float*)d_in[13], whh_w0);
  whh_pack<<<256, 256, 0, stream>>>((const float*)d_in[17], whh_w1);
  bias_sum<<<8, 256, 0, stream>>>((const float*)d_in[6],  (const float*)d_in[7],  bs_c0, 2048);
  bias_sum<<<8, 256, 0, stream>>>((const float*)d_in[10], (const float*)d_in[11], bs_c1, 2048);
  bias_sum<<<8, 256, 0, stream>>>((const float*)d_in[14], (const float*)d_in[15], bs_w0, 2048);
  bias_sum<<<8, 256, 0, stream>>>((const float*)d_in[18], (const float*)d_in[19], bs_w1, 2048);
  embed_gather<<<8192, 256, 0, stream>>>(cid, etab, ce_b, M * 128);

  const int G2048 = (M >> 7) * (2048 >> 7);   // 4096
  const int G512  = (M >> 7) * (512 >> 7);    // 1024
  if (fused) {
    gemm_lds<0, 1><<<G2048, 256, 0, stream>>>(ce_b, 128, wih_c0, bs_c0, xg_c, M, 2048, 128);
    gemm_lds<0, 1><<<G2048, 256, 0, stream>>>(we_b, 768, wih_w0, bs_w0, xg_w, M, 2048, 768);
    lstm_mfma<<<16, 1024, 0, stream>>>(whh_c0, xg_c, comb, 0,
                                       whh_w0, xg_w, comb, 512, T);
    gemm_lds<0, 1><<<G2048, 256, 0, stream>>>(comb, 1024, wih_c1, bs_c1, xg_c, M, 2048, 512);
    gemm_lds<0, 1><<<G2048, 256, 0, stream>>>(comb + 512, 1024, wih_w1, bs_w1, xg_w, M, 2048, 512);
    lstm_mfma<<<16, 1024, 0, stream>>>(whh_c1, xg_c, comb, 0,
                                       whh_w1, xg_w, comb, 512, T);
  } else {
    gemm_lds<0, 1><<<G2048, 256, 0, stream>>>(ce_b, 128, wih_c0, bs_c0, xg_c, M, 2048, 128);
    lstm_mfma<<<8, 1024, 0, stream>>>(whh_c0, xg_c, comb, 0, whh_c0, xg_c, comb, 0, T);
    gemm_lds<0, 1><<<G2048, 256, 0, stream>>>(comb, 1024, wih_c1, bs_c1, xg_c, M, 2048, 512);
    lstm_mfma<<<8, 1024, 0, stream>>>(whh_c1, xg_c, comb, 0, whh_c1, xg_c, comb, 0, T);
    gemm_lds<0, 1><<<G2048, 256, 0, stream>>>(we_b, 768, wih_w0, bs_w0, xg_c, M, 2048, 768);
    lstm_mfma<<<8, 1024, 0, stream>>>(whh_w0, xg_c, comb, 512, whh_w0, xg_c, comb, 512, T);
    gemm_lds<0, 1><<<G2048, 256, 0, stream>>>(comb + 512, 1024, wih_w1, bs_w1, xg_c, M, 2048, 512);
    lstm_mfma<<<8, 1024, 0, stream>>>(whh_w1, xg_c, comb, 512, whh_w1, xg_c, comb, 512, T);
  }
  // ---- classifier ----
  gemm_lds<1, 0><<<G512, 256, 0, stream>>>(comb, 1024, cls1b, (const float*)d_in[21], h1, M, 512, 1024);
  cls2_kernel<<<2048, 256, 0, stream>>>(h1, cls2b, (const float*)d_in[23], logits, M);
  // ---- CRF ----
  crf_num<<<64, 256, 0, stream>>>(logits, tags, (const float*)d_in[24], (const float*)d_in[25],
                                  (const float*)d_in[26], numb, T);
  crf_denom<<<64, 64, 0, stream>>>(logits, (const float*)d_in[24], (const float*)d_in[25],
                                   (const float*)d_in[26], denb, T);
  crf_final<<<1, 64, 0, stream>>>(numb, denb, (float*)d_out);
}

// Round 17
// 3501.875 us; speedup vs baseline: 1.0059x; 1.0059x over previous
//
#include <hip/hip_runtime.h>

#define DEVI __device__ __forceinline__

typedef __attribute__((ext_vector_type(8))) __bf16 bf16x8;
typedef __attribute__((ext_vector_type(4))) float f32x4;

// ---------- scalar helpers ----------
DEVI unsigned short f2b(float f) {           // f32 -> bf16 (RNE)
  unsigned u = __float_as_uint(f);
  u = u + 0x7fffu + ((u >> 16) & 1u);
  return (unsigned short)(u >> 16);
}
DEVI float lo16(unsigned u) { return __uint_as_float(u << 16); }
DEVI float hi16(unsigned u) { return __uint_as_float(u & 0xffff0000u); }
#if __has_builtin(__builtin_amdgcn_rcpf)
DEVI float rcpf(float x) { return __builtin_amdgcn_rcpf(x); }
#else
DEVI float rcpf(float x) { return 1.f / x; }
#endif
DEVI float sigm(float x) { return rcpf(1.f + __expf(-x)); }
DEVI float tanh_f(float x) { return fmaf(2.f, rcpf(1.f + __expf(-2.f * x)), -1.f); }

// ---------- fp8 e4m3fn encode ----------
#if __has_builtin(__builtin_amdgcn_cvt_pk_fp8_f32)
DEVI unsigned char f2e4m3(float f) {
  return (unsigned char)(__builtin_amdgcn_cvt_pk_fp8_f32(f, f, 0, false) & 0xff);
}
#else
DEVI unsigned char f2e4m3(float f) {   // software RNE e4m3fn
  unsigned u = __float_as_uint(f);
  unsigned s = (u >> 31) << 7;
  float a = fabsf(f);
  if (a >= 448.f) return (unsigned char)(s | 0x7e);
  if (a < 0.015625f) {                 // denorm, unit 2^-9
    int m = (int)rintf(a * 512.f);
    if (m >= 8) return (unsigned char)(s | 0x08);
    return (unsigned char)(s | m);
  }
  unsigned ur = u + 0x7FFFF + ((u >> 20) & 1);   // RNE at mantissa bit 20
  int e8 = (int)((ur >> 23) & 255) - 127 + 7;
  unsigned m3 = (ur >> 20) & 7;
  if (e8 > 15 || (e8 == 15 && m3 > 6)) return (unsigned char)(s | 0x7e);
  if (e8 <= 0) return (unsigned char)s;
  return (unsigned char)(s | (e8 << 3) | m3);
}
#endif

// ---------- prep kernels ----------
__global__ void cvt_bf16(const float* __restrict__ in, unsigned short* __restrict__ out, int n) {
  for (int i = blockIdx.x * blockDim.x + threadIdx.x; i < n; i += gridDim.x * blockDim.x)
    out[i] = f2b(in[i]);
}

// Whh (2,1024,256) f32 -> fp8 MFMA-A-fragment order:
// uint2 index = ((d*64 + mt)*8 + kf)*64 + lane; bytes j=0..7:
//   row = mt*16 + (lane&15); unit = row>>2; gate = row&3;
//   k = kf*32 + (lane>>4)*8 + j;  src = W[d][gate*256 + unit][k]
__global__ void whh_pack(const float* __restrict__ W, uint2* __restrict__ out) {
  int idx = blockIdx.x * blockDim.x + threadIdx.x;   // 65536 total
  if (idx >= 65536) return;
  int d = idx >> 15, rem = idx & 32767;
  int mt = rem >> 9, kf = (rem >> 6) & 7, lane = rem & 63;
  int row = mt * 16 + (lane & 15);
  int unit = row >> 2, gate = row & 3;
  int kb = kf * 32 + (lane >> 4) * 8;
  const float* w = W + (((size_t)d * 1024 + gate * 256 + unit) * 256 + kb);
  unsigned lo = 0, hi = 0;
  #pragma unroll
  for (int j = 0; j < 4; ++j) lo |= (unsigned)f2e4m3(w[j]) << (8 * j);
  #pragma unroll
  for (int j = 0; j < 4; ++j) hi |= (unsigned)f2e4m3(w[4 + j]) << (8 * j);
  out[idx] = make_uint2(lo, hi);
}

__global__ void bias_sum(const float* __restrict__ a, const float* __restrict__ b,
                         float* __restrict__ o, int n) {
  int i = blockIdx.x * blockDim.x + threadIdx.x;
  if (i < n) o[i] = a[i] + b[i];
}

__global__ void embed_gather(const int* __restrict__ ids, const float* __restrict__ tab,
                             unsigned short* __restrict__ out, int total) {
  for (int i = blockIdx.x * blockDim.x + threadIdx.x; i < total; i += gridDim.x * blockDim.x) {
    int bt = i >> 7, c = i & 127;
    out[i] = f2b(tab[(size_t)ids[bt] * 128 + c]);
  }
}

// ---------- GEMM (LDS-staged): C[M,N] = act(A[M,K](lda,bf16) @ W[N,K]^T + bias) -> bf16
// 128x128 tile, 256 thr (4 waves), K-step 32. (R11, measured good.)
template <int ACT, int PERM>
__global__ __launch_bounds__(256) void gemm_lds(const unsigned short* __restrict__ A, int lda,
                                                const unsigned short* __restrict__ W,
                                                const float* __restrict__ bias,
                                                unsigned short* __restrict__ C,
                                                int M, int N, int K) {
  const int ntiles = N >> 7;
  const int mt = blockIdx.x / ntiles;
  const int nt = blockIdx.x - mt * ntiles;
  const int m0 = mt << 7, n0 = nt << 7;
  const int tid = threadIdx.x;
  const int w = tid >> 6, lane = tid & 63, r = lane & 15, q = lane >> 4;
  __shared__ unsigned short lsA[4096], lsB[4096];
  f32x4 acc[16];
  #pragma unroll
  for (int i = 0; i < 16; ++i) acc[i] = f32x4{0.f, 0.f, 0.f, 0.f};

  const int srow = tid >> 2, sq = tid & 3;
  const int s0 = (srow << 2) | (sq ^ (srow & 3) ^ ((srow >> 2) & 3));
  const unsigned short* gA = A + (size_t)(m0 + srow) * lda + sq * 8;
  const unsigned short* gB = W + (size_t)(n0 + srow) * K + sq * 8;
  const size_t gAs = (size_t)64 * lda, gBs = (size_t)64 * K;
  const int sw = q ^ (r & 3) ^ ((r >> 2) & 3);

  for (int k0 = 0; k0 < K; k0 += 32) {
    uint4 va0 = *(const uint4*)(gA + k0);
    uint4 va1 = *(const uint4*)(gA + gAs + k0);
    uint4 vb0 = *(const uint4*)(gB + k0);
    uint4 vb1 = *(const uint4*)(gB + gBs + k0);
    *(uint4*)(lsA + s0 * 8) = va0;
    *(uint4*)(lsA + s0 * 8 + 2048) = va1;
    *(uint4*)(lsB + s0 * 8) = vb0;
    *(uint4*)(lsB + s0 * 8 + 2048) = vb1;
    __syncthreads();
    const bf16x8 a0 = *(const bf16x8*)(const void*)(lsA + ((w * 32 + r) * 4 + sw) * 8);
    const bf16x8 a1 = *(const bf16x8*)(const void*)(lsA + ((w * 32 + 16 + r) * 4 + sw) * 8);
    #pragma unroll
    for (int nf = 0; nf < 8; ++nf) {
      const bf16x8 b = *(const bf16x8*)(const void*)(lsB + ((nf * 16 + r) * 4 + sw) * 8);
      acc[nf]     = __builtin_amdgcn_mfma_f32_16x16x32_bf16(a0, b, acc[nf], 0, 0, 0);
      acc[8 + nf] = __builtin_amdgcn_mfma_f32_16x16x32_bf16(a1, b, acc[8 + nf], 0, 0, 0);
    }
    __syncthreads();
  }
  #pragma unroll
  for (int mf = 0; mf < 2; ++mf) {
    const int rbase = m0 + w * 32 + mf * 16 + q * 4;
    #pragma unroll
    for (int nf = 0; nf < 8; ++nf) {
      const f32x4 a = acc[mf * 8 + nf];
      const int col = n0 + nf * 16 + r;
      const float bv = bias[col];
      int oc = col;
      if constexpr (PERM) oc = (col & 1024) | ((col & 255) << 2) | ((col >> 8) & 3);
      #pragma unroll
      for (int i = 0; i < 4; ++i) {
        float v = a[i] + bv;
        if constexpr (ACT) v = fmaxf(v, 0.f);
        C[(size_t)(rbase + i) * N + oc] = f2b(v);
      }
    }
  }
}

// ---------- LSTM recurrence via MFMA fp8, 16 samples per block ----------
// R16 form + LOOP-CARRIED register pin: asm "+v" on each wreg at the TOP of every
// t-iteration makes the weights an opaque loop-carried value -- the compiler cannot
// legally rematerialize the loads (the asm "modifies" them), so 64 weight VGPRs stay
// live and the 256KB/step L2 stream disappears. Verify: VGPR_Count ~110-128, FETCH
// drops to ~66MB. If VGPR shows 64 or scratch appears, this round is falsified.
__global__ __launch_bounds__(1024, 4) void lstm_mfma(
    const uint2* __restrict__ W0, const unsigned short* __restrict__ x0,
    unsigned short* __restrict__ o0, int oo0,
    const uint2* __restrict__ W1, const unsigned short* __restrict__ x1,
    unsigned short* __restrict__ o1, int oo1, int T) {
  const int bid = blockIdx.x;
  const int sg = bid & 3, dir = (bid >> 2) & 1, grp = bid >> 3;
  const uint2* __restrict__ Wp = (grp ? W1 : W0) + (size_t)dir * 32768;
  const unsigned short* __restrict__ xg = grp ? x1 : x0;
  unsigned short* __restrict__ out = grp ? o1 : o0;
  const int outOff = grp ? oo1 : oo0;

  const int tid = threadIdx.x;
  const int w = tid >> 6, lane = tid & 63, q = lane >> 4, n = lane & 15;
  const int b = sg * 16 + n;

  __shared__ long hb[2][512];                 // fp8 h B-fragments (MFMA input)
  __shared__ unsigned short hout[2][16][264]; // bf16 h rows, padded (store staging)
  hb[0][tid & 511] = 0;
  hb[1][tid & 511] = 0;

  // ---- preload this wave's Whh slice into registers (pinned via in-loop asm) ----
  long wreg[32];
  {
    const uint2* ap = Wp + (size_t)(w * 32) * 64 + lane;
    #pragma unroll
    for (int i = 0; i < 32; ++i)
      wreg[i] = __builtin_bit_cast(long, ap[(size_t)i * 64]);
  }

  float c[4] = {0.f, 0.f, 0.f, 0.f};
  const unsigned short* xb = xg + ((size_t)b * T) * 2048 + dir * 1024 + (w * 16 + q) * 4;
  // wave w cooperatively stores sample (sg*16+w)'s output row
  unsigned short* orow = out + ((size_t)(sg * 16 + w) * T) * 1024 + outOff + dir * 256 + lane * 4;

  const int tstep = dir ? -1 : 1;
  int t = dir ? T - 1 : 0;
  // prefetch first step's xg
  uint2 xv[4];
  #pragma unroll
  for (int j = 0; j < 4; ++j)
    xv[j] = *(const uint2*)(xb + (size_t)t * 2048 + j * 16);
  __syncthreads();

  int cur = 0;
  for (int ti = 0; ti < T; ++ti) {
    // loop-carried pin: wreg is input AND output of an opaque asm each iteration;
    // the "modified" values feed the next iteration -> reload is illegal.
    #pragma unroll
    for (int i = 0; i < 32; ++i)
      asm volatile("" : "+v"(wreg[i]));
    // coalesced store of previous step's h (written into hout[cur] last iter)
    if (ti) {
      const uint2 hv = *(const uint2*)&hout[cur][w][lane * 4];
      *(uint2*)(orow + (size_t)(t - tstep) * 1024) = hv;
    }
    // prefetch next step's xg (consumed after next barrier)
    uint2 xn[4];
    if (ti + 1 < T) {
      #pragma unroll
      for (int j = 0; j < 4; ++j)
        xn[j] = *(const uint2*)(xb + (size_t)(t + tstep) * 2048 + j * 16);
    }
    // MFMA: acc[j] = Whh-tile(w*4+j) x h
    f32x4 acc[4];
    #pragma unroll
    for (int j = 0; j < 4; ++j) acc[j] = f32x4{0.f, 0.f, 0.f, 0.f};
    #pragma unroll
    for (int kf = 0; kf < 8; ++kf) {
      const long bf = hb[cur][kf * 64 + q * 16 + n];
      #pragma unroll
      for (int j = 0; j < 4; ++j)
        acc[j] = __builtin_amdgcn_mfma_f32_16x16x32_fp8_fp8(wreg[j * 8 + kf], bf, acc[j], 0, 0, 0);
    }
    // cell update: lane owns (unit u, sample n) fully
    unsigned char* hw = (unsigned char*)&hb[cur ^ 1][0];
    #pragma unroll
    for (int j = 0; j < 4; ++j) {
      const int u = w * 16 + j * 4 + q;
      const float gi = acc[j][0] + lo16(xv[j].x);
      const float gf = acc[j][1] + hi16(xv[j].x);
      const float gg = acc[j][2] + lo16(xv[j].y);
      const float go = acc[j][3] + hi16(xv[j].y);
      c[j] = sigm(gf) * c[j] + sigm(gi) * tanh_f(gg);
      const float h = sigm(go) * tanh_f(c[j]);
      hw[(u >> 3) * 128 + n * 8 + (u & 7)] = f2e4m3(h);
      hout[cur ^ 1][n][u] = f2b(h);
    }
    // lgkmcnt-only barrier: LDS writes visible; global stores/loads NOT drained
    asm volatile("s_waitcnt lgkmcnt(0)\n\ts_barrier" ::: "memory");
    #pragma unroll
    for (int j = 0; j < 4; ++j) xv[j] = xn[j];
    t += tstep;
    cur ^= 1;
  }
  // epilogue: store last step's h
  const uint2 hv = *(const uint2*)&hout[cur][w][lane * 4];
  *(uint2*)(orow + (size_t)(t - tstep) * 1024) = hv;
}

// ---------- classifier layer 2 ----------
__global__ __launch_bounds__(256) void cls2_kernel(const unsigned short* __restrict__ h1,
                                                   const unsigned short* __restrict__ w2,
                                                   const float* __restrict__ b2,
                                                   float* __restrict__ logits, int M) {
  int idx = blockIdx.x * 256 + threadIdx.x;
  int row = idx >> 4, n = idx & 15;
  if (row >= M || n >= 15) return;
  const unsigned* hp = (const unsigned*)(h1 + (size_t)row * 512);
  const unsigned* wp = (const unsigned*)(w2 + (size_t)n * 512);
  float acc = 0.f;
  #pragma unroll 8
  for (int k = 0; k < 256; ++k) {
    unsigned uh = hp[k], uw = wp[k];
    acc = fmaf(lo16(uh), lo16(uw), acc);
    acc = fmaf(hi16(uh), hi16(uw), acc);
  }
  logits[(size_t)row * 16 + n] = acc + b2[n];
}

// ---------- CRF ----------
__global__ __launch_bounds__(256) void crf_num(const float* __restrict__ logits,
                                               const int* __restrict__ tags,
                                               const float* __restrict__ start,
                                               const float* __restrict__ end,
                                               const float* __restrict__ trans,
                                               float* __restrict__ numout, int T) {
  int b = blockIdx.x, tid = threadIdx.x;
  const int* tg = tags + (size_t)b * T;
  float s = 0.f;
  for (int t = tid; t < T; t += 256) {
    int cur = tg[t];
    s += logits[((size_t)b * T + t) * 16 + cur];
    if (t > 0) s += trans[tg[t - 1] * 15 + cur];
  }
  #pragma unroll
  for (int off = 32; off > 0; off >>= 1) s += __shfl_down(s, off, 64);
  __shared__ float red[4];
  if ((tid & 63) == 0) red[tid >> 6] = s;
  __syncthreads();
  if (tid == 0)
    numout[b] = red[0] + red[1] + red[2] + red[3] + start[tg[0]] + end[tg[T - 1]];
}

__global__ void crf_denom(const float* __restrict__ logits, const float* __restrict__ start,
                          const float* __restrict__ end, const float* __restrict__ trans,
                          float* __restrict__ denout, int T) {
  int b = blockIdx.x;
  int lane = threadIdx.x;
  int kp = lane < 15 ? lane : 0;
  float tcol[15];
  #pragma unroll
  for (int k = 0; k < 15; ++k) tcol[k] = trans[k * 15 + kp];
  float score = start[kp] + logits[((size_t)b * T) * 16 + kp];
  for (int t = 1; t < T; ++t) {
    float e = logits[((size_t)b * T + t) * 16 + kp];
    float s[15], m = -3.4e38f;
    #pragma unroll
    for (int k = 0; k < 15; ++k) {
      s[k] = __shfl(score, k, 64) + tcol[k];
      m = fmaxf(m, s[k]);
    }
    float sum = 0.f;
    #pragma unroll
    for (int k = 0; k < 15; ++k) sum += __expf(s[k] - m);
    score = e + m + __logf(sum);
  }
  float x = score + end[kp];
  float m = -3.4e38f;
  #pragma unroll
  for (int k = 0; k < 15; ++k) m = fmaxf(m, __shfl(x, k, 64));
  float sum = 0.f;
  #pragma unroll
  for (int k = 0; k < 15; ++k) sum += __expf(__shfl(x, k, 64) - m);
  if (lane == 0) denout[b] = m + __logf(sum);
}

__global__ void crf_final(const float* __restrict__ num, const float* __restrict__ den,
                          float* __restrict__ out) {
  int l = threadIdx.x;
  float v = den[l] - num[l];
  #pragma unroll
  for (int off = 32; off > 0; off >>= 1) v += __shfl_xor(v, off, 64);
  if (l == 0) out[0] = v * (1.f / 64.f);
}

// ---------- host ----------
extern "C" void kernel_launch(void* const* d_in, const int* in_sizes, int n_in,
                              void* d_out, int out_size, void* d_ws, size_t ws_size,
                              hipStream_t stream) {
  const int B = 64, T = 512, M = B * T;   // 32768
  const float* we   = (const float*)d_in[1];
  const int*   cid  = (const int*)d_in[0];
  const int*   tags = (const int*)d_in[2];
  const float* etab = (const float*)d_in[3];

  char* ws = (char*)d_ws;
  size_t off = 0;
  auto alloc = [&](size_t bytes) -> char* {
    char* p = ws + off;
    off += (bytes + 255) & ~(size_t)255;
    return p;
  };
  // small, permanent
  unsigned short* wih_c0 = (unsigned short*)alloc((size_t)2048 * 128 * 2);
  unsigned short* wih_c1 = (unsigned short*)alloc((size_t)2048 * 512 * 2);
  unsigned short* wih_w0 = (unsigned short*)alloc((size_t)2048 * 768 * 2);
  unsigned short* wih_w1 = (unsigned short*)alloc((size_t)2048 * 512 * 2);
  unsigned short* cls1b  = (unsigned short*)alloc((size_t)512 * 1024 * 2);
  unsigned short* cls2b  = (unsigned short*)alloc((size_t)15 * 512 * 2);
  uint2* whh_c0 = (uint2*)alloc((size_t)65536 * 8);
  uint2* whh_c1 = (uint2*)alloc((size_t)65536 * 8);
  uint2* whh_w0 = (uint2*)alloc((size_t)65536 * 8);
  uint2* whh_w1 = (uint2*)alloc((size_t)65536 * 8);
  float* bs_c0 = (float*)alloc(2048 * 4);
  float* bs_c1 = (float*)alloc(2048 * 4);
  float* bs_w0 = (float*)alloc(2048 * 4);
  float* bs_w1 = (float*)alloc(2048 * 4);
  float* numb = (float*)alloc(64 * 4);
  float* denb = (float*)alloc(64 * 4);
  // big
  unsigned short* comb = (unsigned short*)alloc((size_t)M * 1024 * 2);   // 64 MB
  unsigned short* xg_c = (unsigned short*)alloc((size_t)M * 2048 * 2);   // 128 MB
  const size_t xgw_bytes = (size_t)M * 2048 * 2;
  const bool fused = (off + xgw_bytes) <= ws_size;
  unsigned short* xg_w;
  unsigned short* ce_b;
  unsigned short* we_b;
  if (fused) {
    xg_w = (unsigned short*)alloc(xgw_bytes);
    ce_b = xg_w;          // consumed by g_c0 before g_w0 overwrites xg_w
    we_b = comb;          // consumed by g_w0 before lstm0 writes comb
  } else {
    xg_w = xg_c;
    ce_b = (unsigned short*)alloc((size_t)M * 128 * 2);
    we_b = (unsigned short*)alloc((size_t)M * 768 * 2);
  }
  unsigned short* h1 = xg_c;                        // free after level-1 lstm
  float* logits = (float*)(xg_c + (size_t)24 * 1024 * 1024);   // +48MB into xg_c

  // ---- prep ----
  cvt_bf16<<<1024, 256, 0, stream>>>((const float*)d_in[4],  wih_c0, 2048 * 128);
  cvt_bf16<<<1024, 256, 0, stream>>>((const float*)d_in[8],  wih_c1, 2048 * 512);
  cvt_bf16<<<1024, 256, 0, stream>>>((const float*)d_in[12], wih_w0, 2048 * 768);
  cvt_bf16<<<1024, 256, 0, stream>>>((const float*)d_in[16], wih_w1, 2048 * 512);
  cvt_bf16<<<1024, 256, 0, stream>>>((const float*)d_in[20], cls1b, 512 * 1024);
  cvt_bf16<<<64, 256, 0, stream>>>((const float*)d_in[22], cls2b, 15 * 512);
  cvt_bf16<<<4096, 256, 0, stream>>>(we, we_b, M * 768);
  whh_pack<<<256, 256, 0, stream>>>((const float*)d_in[5],  whh_c0);
  whh_pack<<<256, 256, 0, stream>>>((const float*)d_in[9],  whh_c1);
  whh_pack<<<256, 256, 0, stream>>>((const float*)d_in[13], whh_w0);
  whh_pack<<<256, 256, 0, stream>>>((const float*)d_in[17], whh_w1);
  bias_sum<<<8, 256, 0, stream>>>((const float*)d_in[6],  (const float*)d_in[7],  bs_c0, 2048);
  bias_sum<<<8, 256, 0, stream>>>((const float*)d_in[10], (const float*)d_in[11], bs_c1, 2048);
  bias_sum<<<8, 256, 0, stream>>>((const float*)d_in[14], (const float*)d_in[15], bs_w0, 2048);
  bias_sum<<<8, 256, 0, stream>>>((const float*)d_in[18], (const float*)d_in[19], bs_w1, 2048);
  embed_gather<<<8192, 256, 0, stream>>>(cid, etab, ce_b, M * 128);

  const int G2048 = (M >> 7) * (2048 >> 7);   // 4096
  const int G512  = (M >> 7) * (512 >> 7);    // 1024
  if (fused) {
    gemm_lds<0, 1><<<G2048, 256, 0, stream>>>(ce_b, 128, wih_c0, bs_c0, xg_c, M, 2048, 128);
    gemm_lds<0, 1><<<G2048, 256, 0, stream>>>(we_b, 768, wih_w0, bs_w0, xg_w, M, 2048, 768);
    lstm_mfma<<<16, 1024, 0, stream>>>(whh_c0, xg_c, comb, 0,
                                       whh_w0, xg_w, comb, 512, T);
    gemm_lds<0, 1><<<G2048, 256, 0, stream>>>(comb, 1024, wih_c1, bs_c1, xg_c, M, 2048, 512);
    gemm_lds<0, 1><<<G2048, 256, 0, stream>>>(comb + 512, 1024, wih_w1, bs_w1, xg_w, M, 2048, 512);
    lstm_mfma<<<16, 1024, 0, stream>>>(whh_c1, xg_c, comb, 0,
                                       whh_w1, xg_w, comb, 512, T);
  } else {
    gemm_lds<0, 1><<<G2048, 256, 0, stream>>>(ce_b, 128, wih_c0, bs_c0, xg_c, M, 2048, 128);
    lstm_mfma<<<8, 1024, 0, stream>>>(whh_c0, xg_c, comb, 0, whh_c0, xg_c, comb, 0, T);
    gemm_lds<0, 1><<<G2048, 256, 0, stream>>>(comb, 1024, wih_c1, bs_c1, xg_c, M, 2048, 512);
    lstm_mfma<<<8, 1024, 0, stream>>>(whh_c1, xg_c, comb, 0, whh_c1, xg_c, comb, 0, T);
    gemm_lds<0, 1><<<G2048, 256, 0, stream>>>(we_b, 768, wih_w0, bs_w0, xg_c, M, 2048, 768);
    lstm_mfma<<<8, 1024, 0, stream>>>(whh_w0, xg_c, comb, 512, whh_w0, xg_c, comb, 512, T);
    gemm_lds<0, 1><<<G2048, 256, 0, stream>>>(comb + 512, 1024, wih_w1, bs_w1, xg_c, M, 2048, 512);
    lstm_mfma<<<8, 1024, 0, stream>>>(whh_w1, xg_c, comb, 512, whh_w1, xg_c, comb, 512, T);
  }
  // ---- classifier ----
  gemm_lds<1, 0><<<G512, 256, 0, stream>>>(comb, 1024, cls1b, (const float*)d_in[21], h1, M, 512, 1024);
  cls2_kernel<<<2048, 256, 0, stream>>>(h1, cls2b, (const float*)d_in[23], logits, M);
  // ---- CRF ----
  crf_num<<<64, 256, 0, stream>>>(logits, tags, (const float*)d_in[24], (const float*)d_in[25],
                                  (const float*)d_in[26], numb, T);
  crf_denom<<<64, 64, 0, stream>>>(logits, (const float*)d_in[24], (const float*)d_in[25],
                                   (const float*)d_in[26], denb, T);
  crf_final<<<1, 64, 0, stream>>>(numb, denb, (float*)d_out);
}

// Round 18
// 3494.498 us; speedup vs baseline: 1.0080x; 1.0021x over previous
//
#include <hip/hip_runtime.h>

#define DEVI __device__ __forceinline__

typedef __attribute__((ext_vector_type(8))) __bf16 bf16x8;
typedef __attribute__((ext_vector_type(4))) float f32x4;

// ---------- scalar helpers ----------
DEVI unsigned short f2b(float f) {           // f32 -> bf16 (RNE)
  unsigned u = __float_as_uint(f);
  u = u + 0x7fffu + ((u >> 16) & 1u);
  return (unsigned short)(u >> 16);
}
DEVI float lo16(unsigned u) { return __uint_as_float(u << 16); }
DEVI float hi16(unsigned u) { return __uint_as_float(u & 0xffff0000u); }
#if __has_builtin(__builtin_amdgcn_rcpf)
DEVI float rcpf(float x) { return __builtin_amdgcn_rcpf(x); }
#else
DEVI float rcpf(float x) { return 1.f / x; }
#endif
DEVI float sigm(float x) { return rcpf(1.f + __expf(-x)); }
DEVI float tanh_f(float x) { return fmaf(2.f, rcpf(1.f + __expf(-2.f * x)), -1.f); }

// ---------- fp8 e4m3fn encode ----------
#if __has_builtin(__builtin_amdgcn_cvt_pk_fp8_f32)
DEVI unsigned char f2e4m3(float f) {
  return (unsigned char)(__builtin_amdgcn_cvt_pk_fp8_f32(f, f, 0, false) & 0xff);
}
#else
DEVI unsigned char f2e4m3(float f) {   // software RNE e4m3fn
  unsigned u = __float_as_uint(f);
  unsigned s = (u >> 31) << 7;
  float a = fabsf(f);
  if (a >= 448.f) return (unsigned char)(s | 0x7e);
  if (a < 0.015625f) {                 // denorm, unit 2^-9
    int m = (int)rintf(a * 512.f);
    if (m >= 8) return (unsigned char)(s | 0x08);
    return (unsigned char)(s | m);
  }
  unsigned ur = u + 0x7FFFF + ((u >> 20) & 1);   // RNE at mantissa bit 20
  int e8 = (int)((ur >> 23) & 255) - 127 + 7;
  unsigned m3 = (ur >> 20) & 7;
  if (e8 > 15 || (e8 == 15 && m3 > 6)) return (unsigned char)(s | 0x7e);
  if (e8 <= 0) return (unsigned char)s;
  return (unsigned char)(s | (e8 << 3) | m3);
}
#endif

// ---------- async global->LDS (16B per lane; dest = wave base + lane*16) ----------
#if __has_builtin(__builtin_amdgcn_global_load_lds)
#define HAS_GLOAD_LDS 1
DEVI void gload_lds16(const void* g, void* l) {
  __builtin_amdgcn_global_load_lds((const __attribute__((address_space(1))) void*)g,
                                   (__attribute__((address_space(3))) void*)l, 16, 0, 0);
}
#else
#define HAS_GLOAD_LDS 0
#endif

// ---------- prep kernels ----------
__global__ void cvt_bf16(const float* __restrict__ in, unsigned short* __restrict__ out, int n) {
  for (int i = blockIdx.x * blockDim.x + threadIdx.x; i < n; i += gridDim.x * blockDim.x)
    out[i] = f2b(in[i]);
}

// Whh (2,1024,256) f32 -> fp8 MFMA-A-fragment order:
// uint2 index = ((d*64 + mt)*8 + kf)*64 + lane; bytes j=0..7:
//   row = mt*16 + (lane&15); unit = row>>2; gate = row&3;
//   k = kf*32 + (lane>>4)*8 + j;  src = W[d][gate*256 + unit][k]
__global__ void whh_pack(const float* __restrict__ W, uint2* __restrict__ out) {
  int idx = blockIdx.x * blockDim.x + threadIdx.x;   // 65536 total
  if (idx >= 65536) return;
  int d = idx >> 15, rem = idx & 32767;
  int mt = rem >> 9, kf = (rem >> 6) & 7, lane = rem & 63;
  int row = mt * 16 + (lane & 15);
  int unit = row >> 2, gate = row & 3;
  int kb = kf * 32 + (lane >> 4) * 8;
  const float* w = W + (((size_t)d * 1024 + gate * 256 + unit) * 256 + kb);
  unsigned lo = 0, hi = 0;
  #pragma unroll
  for (int j = 0; j < 4; ++j) lo |= (unsigned)f2e4m3(w[j]) << (8 * j);
  #pragma unroll
  for (int j = 0; j < 4; ++j) hi |= (unsigned)f2e4m3(w[4 + j]) << (8 * j);
  out[idx] = make_uint2(lo, hi);
}

__global__ void bias_sum(const float* __restrict__ a, const float* __restrict__ b,
                         float* __restrict__ o, int n) {
  int i = blockIdx.x * blockDim.x + threadIdx.x;
  if (i < n) o[i] = a[i] + b[i];
}

__global__ void embed_gather(const int* __restrict__ ids, const float* __restrict__ tab,
                             unsigned short* __restrict__ out, int total) {
  for (int i = blockIdx.x * blockDim.x + threadIdx.x; i < total; i += gridDim.x * blockDim.x) {
    int bt = i >> 7, c = i & 127;
    out[i] = f2b(tab[(size_t)ids[bt] * 128 + c]);
  }
}

// ---------- GEMM (LDS-staged): C[M,N] = act(A[M,K](lda,bf16) @ W[N,K]^T + bias) -> bf16
// 128x128 tile, 256 thr (4 waves), K-step 32. Staging via global_load_lds width=16
// (m151: 874 vs 646 TF for reg-staging at this tile). LDS layout [128][32] row-major:
// thread tid stages (row=tid>>2, kchunk=tid&3) -> LDS byte tid*16 = row*64+kchunk*16,
// exactly the wave-base + lane*16 pattern gload_lds writes. Frag reads linear.
template <int ACT, int PERM>
__global__ __launch_bounds__(256) void gemm_lds(const unsigned short* __restrict__ A, int lda,
                                                const unsigned short* __restrict__ W,
                                                const float* __restrict__ bias,
                                                unsigned short* __restrict__ C,
                                                int M, int N, int K) {
  const int ntiles = N >> 7;
  const int mt = blockIdx.x / ntiles;
  const int nt = blockIdx.x - mt * ntiles;
  const int m0 = mt << 7, n0 = nt << 7;
  const int tid = threadIdx.x;
  const int w = tid >> 6, lane = tid & 63, r = lane & 15, q = lane >> 4;
  __shared__ unsigned short lsA[4096], lsB[4096];   // [128][32] row-major
  f32x4 acc[16];
  #pragma unroll
  for (int i = 0; i < 16; ++i) acc[i] = f32x4{0.f, 0.f, 0.f, 0.f};

  const int srow = tid >> 2, sq = tid & 3;
  const unsigned short* gA0 = A + (size_t)(m0 + srow) * lda + sq * 8;
  const unsigned short* gA1 = gA0 + (size_t)64 * lda;
  const unsigned short* gB0 = W + (size_t)(n0 + srow) * K + sq * 8;
  const unsigned short* gB1 = gB0 + (size_t)64 * K;
#if HAS_GLOAD_LDS
  char* ldsA0 = (char*)lsA + w * 1024;
  char* ldsA1 = (char*)lsA + 4096 + w * 1024;
  char* ldsB0 = (char*)lsB + w * 1024;
  char* ldsB1 = (char*)lsB + 4096 + w * 1024;
#endif

  for (int k0 = 0; k0 < K; k0 += 32) {
#if HAS_GLOAD_LDS
    gload_lds16(gA0 + k0, ldsA0);
    gload_lds16(gA1 + k0, ldsA1);
    gload_lds16(gB0 + k0, ldsB0);
    gload_lds16(gB1 + k0, ldsB1);
#else
    *(uint4*)((char*)lsA + (size_t)tid * 16)        = *(const uint4*)(gA0 + k0);
    *(uint4*)((char*)lsA + 4096 + (size_t)tid * 16) = *(const uint4*)(gA1 + k0);
    *(uint4*)((char*)lsB + (size_t)tid * 16)        = *(const uint4*)(gB0 + k0);
    *(uint4*)((char*)lsB + 4096 + (size_t)tid * 16) = *(const uint4*)(gB1 + k0);
#endif
    __syncthreads();
    const bf16x8 a0 = *(const bf16x8*)(const void*)((char*)lsA + (w * 32 + r) * 64 + q * 16);
    const bf16x8 a1 = *(const bf16x8*)(const void*)((char*)lsA + (w * 32 + 16 + r) * 64 + q * 16);
    #pragma unroll
    for (int nf = 0; nf < 8; ++nf) {
      const bf16x8 b = *(const bf16x8*)(const void*)((char*)lsB + (nf * 16 + r) * 64 + q * 16);
      acc[nf]     = __builtin_amdgcn_mfma_f32_16x16x32_bf16(a0, b, acc[nf], 0, 0, 0);
      acc[8 + nf] = __builtin_amdgcn_mfma_f32_16x16x32_bf16(a1, b, acc[8 + nf], 0, 0, 0);
    }
    __syncthreads();
  }
  // D layout (m89-verified): col = lane&15, row = (lane>>4)*4 + reg
  #pragma unroll
  for (int mf = 0; mf < 2; ++mf) {
    const int rbase = m0 + w * 32 + mf * 16 + q * 4;
    #pragma unroll
    for (int nf = 0; nf < 8; ++nf) {
      const f32x4 a = acc[mf * 8 + nf];
      const int col = n0 + nf * 16 + r;
      const float bv = bias[col];
      int oc = col;
      if constexpr (PERM) oc = (col & 1024) | ((col & 255) << 2) | ((col >> 8) & 3);
      #pragma unroll
      for (int i = 0; i < 4; ++i) {
        float v = a[i] + bv;
        if constexpr (ACT) v = fmaxf(v, 0.f);
        C[(size_t)(rbase + i) * N + oc] = f2b(v);
      }
    }
  }
}

// ---------- LSTM recurrence via MFMA fp8, 16 samples per block (R17 form, best: 1202us) ----------
__global__ __launch_bounds__(1024, 4) void lstm_mfma(
    const uint2* __restrict__ W0, const unsigned short* __restrict__ x0,
    unsigned short* __restrict__ o0, int oo0,
    const uint2* __restrict__ W1, const unsigned short* __restrict__ x1,
    unsigned short* __restrict__ o1, int oo1, int T) {
  const int bid = blockIdx.x;
  const int sg = bid & 3, dir = (bid >> 2) & 1, grp = bid >> 3;
  const uint2* __restrict__ Wp = (grp ? W1 : W0) + (size_t)dir * 32768;
  const unsigned short* __restrict__ xg = grp ? x1 : x0;
  unsigned short* __restrict__ out = grp ? o1 : o0;
  const int outOff = grp ? oo1 : oo0;

  const int tid = threadIdx.x;
  const int w = tid >> 6, lane = tid & 63, q = lane >> 4, n = lane & 15;
  const int b = sg * 16 + n;

  __shared__ long hb[2][512];                 // fp8 h B-fragments (MFMA input)
  __shared__ unsigned short hout[2][16][264]; // bf16 h rows, padded (store staging)
  hb[0][tid & 511] = 0;
  hb[1][tid & 511] = 0;

  // ---- preload this wave's Whh slice (remat'd as one early load batch; do not remove) ----
  long wreg[32];
  {
    const uint2* ap = Wp + (size_t)(w * 32) * 64 + lane;
    #pragma unroll
    for (int i = 0; i < 32; ++i)
      wreg[i] = __builtin_bit_cast(long, ap[(size_t)i * 64]);
  }

  float c[4] = {0.f, 0.f, 0.f, 0.f};
  const unsigned short* xb = xg + ((size_t)b * T) * 2048 + dir * 1024 + (w * 16 + q) * 4;
  unsigned short* orow = out + ((size_t)(sg * 16 + w) * T) * 1024 + outOff + dir * 256 + lane * 4;

  const int tstep = dir ? -1 : 1;
  int t = dir ? T - 1 : 0;
  uint2 xv[4];
  #pragma unroll
  for (int j = 0; j < 4; ++j)
    xv[j] = *(const uint2*)(xb + (size_t)t * 2048 + j * 16);
  __syncthreads();

  int cur = 0;
  for (int ti = 0; ti < T; ++ti) {
    #pragma unroll
    for (int i = 0; i < 32; ++i)
      asm volatile("" : "+v"(wreg[i]));
    if (ti) {
      const uint2 hv = *(const uint2*)&hout[cur][w][lane * 4];
      *(uint2*)(orow + (size_t)(t - tstep) * 1024) = hv;
    }
    uint2 xn[4];
    if (ti + 1 < T) {
      #pragma unroll
      for (int j = 0; j < 4; ++j)
        xn[j] = *(const uint2*)(xb + (size_t)(t + tstep) * 2048 + j * 16);
    }
    f32x4 acc[4];
    #pragma unroll
    for (int j = 0; j < 4; ++j) acc[j] = f32x4{0.f, 0.f, 0.f, 0.f};
    #pragma unroll
    for (int kf = 0; kf < 8; ++kf) {
      const long bf = hb[cur][kf * 64 + q * 16 + n];
      #pragma unroll
      for (int j = 0; j < 4; ++j)
        acc[j] = __builtin_amdgcn_mfma_f32_16x16x32_fp8_fp8(wreg[j * 8 + kf], bf, acc[j], 0, 0, 0);
    }
    unsigned char* hw = (unsigned char*)&hb[cur ^ 1][0];
    #pragma unroll
    for (int j = 0; j < 4; ++j) {
      const int u = w * 16 + j * 4 + q;
      const float gi = acc[j][0] + lo16(xv[j].x);
      const float gf = acc[j][1] + hi16(xv[j].x);
      const float gg = acc[j][2] + lo16(xv[j].y);
      const float go = acc[j][3] + hi16(xv[j].y);
      c[j] = sigm(gf) * c[j] + sigm(gi) * tanh_f(gg);
      const float h = sigm(go) * tanh_f(c[j]);
      hw[(u >> 3) * 128 + n * 8 + (u & 7)] = f2e4m3(h);
      hout[cur ^ 1][n][u] = f2b(h);
    }
    asm volatile("s_waitcnt lgkmcnt(0)\n\ts_barrier" ::: "memory");
    #pragma unroll
    for (int j = 0; j < 4; ++j) xv[j] = xn[j];
    t += tstep;
    cur ^= 1;
  }
  const uint2 hv = *(const uint2*)&hout[cur][w][lane * 4];
  *(uint2*)(orow + (size_t)(t - tstep) * 1024) = hv;
}

// ---------- classifier layer 2 ----------
__global__ __launch_bounds__(256) void cls2_kernel(const unsigned short* __restrict__ h1,
                                                   const unsigned short* __restrict__ w2,
                                                   const float* __restrict__ b2,
                                                   float* __restrict__ logits, int M) {
  int idx = blockIdx.x * 256 + threadIdx.x;
  int row = idx >> 4, n = idx & 15;
  if (row >= M || n >= 15) return;
  const unsigned* hp = (const unsigned*)(h1 + (size_t)row * 512);
  const unsigned* wp = (const unsigned*)(w2 + (size_t)n * 512);
  float acc = 0.f;
  #pragma unroll 8
  for (int k = 0; k < 256; ++k) {
    unsigned uh = hp[k], uw = wp[k];
    acc = fmaf(lo16(uh), lo16(uw), acc);
    acc = fmaf(hi16(uh), hi16(uw), acc);
  }
  logits[(size_t)row * 16 + n] = acc + b2[n];
}

// ---------- CRF ----------
__global__ __launch_bounds__(256) void crf_num(const float* __restrict__ logits,
                                               const int* __restrict__ tags,
                                               const float* __restrict__ start,
                                               const float* __restrict__ end,
                                               const float* __restrict__ trans,
                                               float* __restrict__ numout, int T) {
  int b = blockIdx.x, tid = threadIdx.x;
  const int* tg = tags + (size_t)b * T;
  float s = 0.f;
  for (int t = tid; t < T; t += 256) {
    int cur = tg[t];
    s += logits[((size_t)b * T + t) * 16 + cur];
    if (t > 0) s += trans[tg[t - 1] * 15 + cur];
  }
  #pragma unroll
  for (int off = 32; off > 0; off >>= 1) s += __shfl_down(s, off, 64);
  __shared__ float red[4];
  if ((tid & 63) == 0) red[tid >> 6] = s;
  __syncthreads();
  if (tid == 0)
    numout[b] = red[0] + red[1] + red[2] + red[3] + start[tg[0]] + end[tg[T - 1]];
}

__global__ void crf_denom(const float* __restrict__ logits, const float* __restrict__ start,
                          const float* __restrict__ end, const float* __restrict__ trans,
                          float* __restrict__ denout, int T) {
  int b = blockIdx.x;
  int lane = threadIdx.x;
  int kp = lane < 15 ? lane : 0;
  float tcol[15];
  #pragma unroll
  for (int k = 0; k < 15; ++k) tcol[k] = trans[k * 15 + kp];
  float score = start[kp] + logits[((size_t)b * T) * 16 + kp];
  for (int t = 1; t < T; ++t) {
    float e = logits[((size_t)b * T + t) * 16 + kp];
    float s[15], m = -3.4e38f;
    #pragma unroll
    for (int k = 0; k < 15; ++k) {
      s[k] = __shfl(score, k, 64) + tcol[k];
      m = fmaxf(m, s[k]);
    }
    float sum = 0.f;
    #pragma unroll
    for (int k = 0; k < 15; ++k) sum += __expf(s[k] - m);
    score = e + m + __logf(sum);
  }
  float x = score + end[kp];
  float m = -3.4e38f;
  #pragma unroll
  for (int k = 0; k < 15; ++k) m = fmaxf(m, __shfl(x, k, 64));
  float sum = 0.f;
  #pragma unroll
  for (int k = 0; k < 15; ++k) sum += __expf(__shfl(x, k, 64) - m);
  if (lane == 0) denout[b] = m + __logf(sum);
}

__global__ void crf_final(const float* __restrict__ num, const float* __restrict__ den,
                          float* __restrict__ out) {
  int l = threadIdx.x;
  float v = den[l] - num[l];
  #pragma unroll
  for (int off = 32; off > 0; off >>= 1) v += __shfl_xor(v, off, 64);
  if (l == 0) out[0] = v * (1.f / 64.f);
}

// ---------- host ----------
extern "C" void kernel_launch(void* const* d_in, const int* in_sizes, int n_in,
                              void* d_out, int out_size, void* d_ws, size_t ws_size,
                              hipStream_t stream) {
  const int B = 64, T = 512, M = B * T;   // 32768
  const float* we   = (const float*)d_in[1];
  const int*   cid  = (const int*)d_in[0];
  const int*   tags = (const int*)d_in[2];
  const float* etab = (const float*)d_in[3];

  char* ws = (char*)d_ws;
  size_t off = 0;
  auto alloc = [&](size_t bytes) -> char* {
    char* p = ws + off;
    off += (bytes + 255) & ~(size_t)255;
    return p;
  };
  // small, permanent
  unsigned short* wih_c0 = (unsigned short*)alloc((size_t)2048 * 128 * 2);
  unsigned short* wih_c1 = (unsigned short*)alloc((size_t)2048 * 512 * 2);
  unsigned short* wih_w0 = (unsigned short*)alloc((size_t)2048 * 768 * 2);
  unsigned short* wih_w1 = (unsigned short*)alloc((size_t)2048 * 512 * 2);
  unsigned short* cls1b  = (unsigned short*)alloc((size_t)512 * 1024 * 2);
  unsigned short* cls2b  = (unsigned short*)alloc((size_t)15 * 512 * 2);
  uint2* whh_c0 = (uint2*)alloc((size_t)65536 * 8);
  uint2* whh_c1 = (uint2*)alloc((size_t)65536 * 8);
  uint2* whh_w0 = (uint2*)alloc((size_t)65536 * 8);
  uint2* whh_w1 = (uint2*)alloc((size_t)65536 * 8);
  float* bs_c0 = (float*)alloc(2048 * 4);
  float* bs_c1 = (float*)alloc(2048 * 4);
  float* bs_w0 = (float*)alloc(2048 * 4);
  float* bs_w1 = (float*)alloc(2048 * 4);
  float* numb = (float*)alloc(64 * 4);
  float* denb = (float*)alloc(64 * 4);
  // big
  unsigned short* comb = (unsigned short*)alloc((size_t)M * 1024 * 2);   // 64 MB
  unsigned short* xg_c = (unsigned short*)alloc((size_t)M * 2048 * 2);   // 128 MB
  const size_t xgw_bytes = (size_t)M * 2048 * 2;
  const bool fused = (off + xgw_bytes) <= ws_size;
  unsigned short* xg_w;
  unsigned short* ce_b;
  unsigned short* we_b;
  if (fused) {
    xg_w = (unsigned short*)alloc(xgw_bytes);
    ce_b = xg_w;          // consumed by g_c0 before g_w0 overwrites xg_w
    we_b = comb;          // consumed by g_w0 before lstm0 writes comb
  } else {
    xg_w = xg_c;
    ce_b = (unsigned short*)alloc((size_t)M * 128 * 2);
    we_b = (unsigned short*)alloc((size_t)M * 768 * 2);
  }
  unsigned short* h1 = xg_c;                        // free after level-1 lstm
  float* logits = (float*)(xg_c + (size_t)24 * 1024 * 1024);   // +48MB into xg_c

  // ---- prep ----
  cvt_bf16<<<1024, 256, 0, stream>>>((const float*)d_in[4],  wih_c0, 2048 * 128);
  cvt_bf16<<<1024, 256, 0, stream>>>((const float*)d_in[8],  wih_c1, 2048 * 512);
  cvt_bf16<<<1024, 256, 0, stream>>>((const float*)d_in[12], wih_w0, 2048 * 768);
  cvt_bf16<<<1024, 256, 0, stream>>>((const float*)d_in[16], wih_w1, 2048 * 512);
  cvt_bf16<<<1024, 256, 0, stream>>>((const float*)d_in[20], cls1b, 512 * 1024);
  cvt_bf16<<<64, 256, 0, stream>>>((const float*)d_in[22], cls2b, 15 * 512);
  cvt_bf16<<<4096, 256, 0, stream>>>(we, we_b, M * 768);
  whh_pack<<<256, 256, 0, stream>>>((const float*)d_in[5],  whh_c0);
  whh_pack<<<256, 256, 0, stream>>>((const float*)d_in[9],  whh_c1);
  whh_pack<<<256, 256, 0, stream>>>((const float*)d_in[13], whh_w0);
  whh_pack<<<256, 256, 0, stream>>>((const float*)d_in[17], whh_w1);
  bias_sum<<<8, 256, 0, stream>>>((const float*)d_in[6],  (const float*)d_in[7],  bs_c0, 2048);
  bias_sum<<<8, 256, 0, stream>>>((const float*)d_in[10], (const float*)d_in[11], bs_c1, 2048);
  bias_sum<<<8, 256, 0, stream>>>((const float*)d_in[14], (const float*)d_in[15], bs_w0, 2048);
  bias_sum<<<8, 256, 0, stream>>>((const float*)d_in[18], (const float*)d_in[19], bs_w1, 2048);
  embed_gather<<<8192, 256, 0, stream>>>(cid, etab, ce_b, M * 128);

  const int G2048 = (M >> 7) * (2048 >> 7);   // 4096
  const int G512  = (M >> 7) * (512 >> 7);    // 1024
  if (fused) {
    gemm_lds<0, 1><<<G2048, 256, 0, stream>>>(ce_b, 128, wih_c0, bs_c0, xg_c, M, 2048, 128);
    gemm_lds<0, 1><<<G2048, 256, 0, stream>>>(we_b, 768, wih_w0, bs_w0, xg_w, M, 2048, 768);
    lstm_mfma<<<16, 1024, 0, stream>>>(whh_c0, xg_c, comb, 0,
                                       whh_w0, xg_w, comb, 512, T);
    gemm_lds<0, 1><<<G2048, 256, 0, stream>>>(comb, 1024, wih_c1, bs_c1, xg_c, M, 2048, 512);
    gemm_lds<0, 1><<<G2048, 256, 0, stream>>>(comb + 512, 1024, wih_w1, bs_w1, xg_w, M, 2048, 512);
    lstm_mfma<<<16, 1024, 0, stream>>>(whh_c1, xg_c, comb, 0,
                                       whh_w1, xg_w, comb, 512, T);
  } else {
    gemm_lds<0, 1><<<G2048, 256, 0, stream>>>(ce_b, 128, wih_c0, bs_c0, xg_c, M, 2048, 128);
    lstm_mfma<<<8, 1024, 0, stream>>>(whh_c0, xg_c, comb, 0, whh_c0, xg_c, comb, 0, T);
    gemm_lds<0, 1><<<G2048, 256, 0, stream>>>(comb, 1024, wih_c1, bs_c1, xg_c, M, 2048, 512);
    lstm_mfma<<<8, 1024, 0, stream>>>(whh_c1, xg_c, comb, 0, whh_c1, xg_c, comb, 0, T);
    gemm_lds<0, 1><<<G2048, 256, 0, stream>>>(we_b, 768, wih_w0, bs_w0, xg_c, M, 2048, 768);
    lstm_mfma<<<8, 1024, 0, stream>>>(whh_w0, xg_c, comb, 512, whh_w0, xg_c, comb, 512, T);
    gemm_lds<0, 1><<<G2048, 256, 0, stream>>>(comb + 512, 1024, wih_w1, bs_w1, xg_c, M, 2048, 512);
    lstm_mfma<<<8, 1024, 0, stream>>>(whh_w1, xg_c, comb, 512, whh_w1, xg_c, comb, 512, T);
  }
  // ---- classifier ----
  gemm_lds<1, 0><<<G512, 256, 0, stream>>>(comb, 1024, cls1b, (const float*)d_in[21], h1, M, 512, 1024);
  cls2_kernel<<<2048, 256, 0, stream>>>(h1, cls2b, (const float*)d_in[23], logits, M);
  // ---- CRF ----
  crf_num<<<64, 256, 0, stream>>>(logits, tags, (const float*)d_in[24], (const float*)d_in[25],
                                  (const float*)d_in[26], numb, T);
  crf_denom<<<64, 64, 0, stream>>>(logits, (const float*)d_in[24], (const float*)d_in[25],
                                   (const float*)d_in[26], denb, T);
  crf_final<<<1, 64, 0, stream>>>(numb, denb, (float*)d_out);
}